// Round 1
// baseline (273.889 us; speedup 1.0000x reference)
//
#include <hip/hip_runtime.h>
#include <math.h>

#define N     4096
#define NIMG  2048
#define TILE  32
#define HALO  4
#define SW    (TILE + 2*HALO)   // 40

// Gaussian kernel sigma=1, r=4, normalized (double-precision eval of the
// reference's float32 formula; differences ~1e-7 rel, threshold is 2.3e-2).
#define KW0 0.00013383063f
#define KW1 0.00443186160f
#define KW2 0.05399112800f
#define KW3 0.24197144000f
#define KW4 0.39894346870f

__device__ __forceinline__ int sym_map(int g) {
    // np.pad mode='symmetric': -1 -> 0, -2 -> 1; N -> N-1, N+1 -> N-2
    g = (g < 0) ? (-1 - g) : g;
    g = (g >= N) ? (2 * N - 1 - g) : g;
    return g;
}

// D[y][x] = R[4095-x][y] + 0.01*noise[y][x], where R = bilinear x2 upsample of img.
__device__ __forceinline__ float compute_D(const float* __restrict__ img,
                                           const float* __restrict__ noise,
                                           int gy, int gx) {
    float nval = noise[gy * N + gx];

    int u = (N - 1) - gx;   // row into R
    int v = gy;             // col into R

    // taps for index t: even t=2j -> 0.25*in[j-1] + 0.75*in[j]
    //                   odd  t=2j+1 -> 0.75*in[j] + 0.25*in[j+1]  (clamped)
    int r0 = (u - 1) >> 1;          // arithmetic shift: u=0 -> -1
    int r1 = r0 + 1;
    float wr1 = (u & 1) ? 0.25f : 0.75f;
    float wr0 = 1.0f - wr1;
    r0 = max(r0, 0);
    r1 = min(r1, NIMG - 1);

    int c0 = (v - 1) >> 1;
    int c1 = c0 + 1;
    float wc1 = (v & 1) ? 0.25f : 0.75f;
    float wc0 = 1.0f - wc1;
    c0 = max(c0, 0);
    c1 = min(c1, NIMG - 1);

    const float* row0 = img + (size_t)r0 * NIMG;
    const float* row1 = img + (size_t)r1 * NIMG;
    float top = wc0 * row0[c0] + wc1 * row0[c1];
    float bot = wc0 * row1[c0] + wc1 * row1[c1];
    float rv  = wr0 * top + wr1 * bot;

    return rv + 0.01f * nval;
}

__global__ __launch_bounds__(256, 2)
void TensorAugment_79216376807666_kernel(const float* __restrict__ img,
                                         const float* __restrict__ noise,
                                         float* __restrict__ out) {
    __shared__ float S[SW][SW];     // D tile + halo: rows y0-4..y0+35, cols x0-4..x0+35
    __shared__ float V[TILE][SW];   // vertically blurred, still with x halo

    const int x0 = blockIdx.x * TILE;
    const int y0 = blockIdx.y * TILE;
    const int tid = threadIdx.x;    // 0..255

    const float kk[9] = {KW0, KW1, KW2, KW3, KW4, KW3, KW2, KW1, KW0};

    // ---- Stage 1: build D tile (with symmetric-padded halo) in LDS ----
    for (int idx = tid; idx < SW * SW; idx += 256) {
        int ly = idx / SW;
        int lx = idx - ly * SW;
        int gy = sym_map(y0 - HALO + ly);
        int gx = sym_map(x0 - HALO + lx);
        S[ly][lx] = compute_D(img, noise, gy, gx);
    }
    __syncthreads();

    // ---- Stage 2: vertical 9-tap blur -> V[32][40] ----
    for (int idx = tid; idx < TILE * SW; idx += 256) {
        int r = idx / SW;
        int c = idx - r * SW;
        float acc = 0.0f;
#pragma unroll
        for (int i = 0; i < 9; ++i) acc = fmaf(kk[i], S[r + i][c], acc);
        V[r][c] = acc;
    }
    __syncthreads();

    // ---- Stage 3: horizontal 9-tap blur + clip + log1p, coalesced store ----
    const int lx = tid & 31;
    const int ly8 = tid >> 5;       // 0..7
#pragma unroll
    for (int rr = 0; rr < 4; ++rr) {
        int r = ly8 + rr * 8;       // 0..31
        float acc = 0.0f;
#pragma unroll
        for (int j = 0; j < 9; ++j) acc = fmaf(kk[j], V[r][lx + j], acc);
        acc = fmaxf(acc, 0.0f);
        out[(size_t)(y0 + r) * N + (x0 + lx)] = log1pf(acc);
    }
}

extern "C" void kernel_launch(void* const* d_in, const int* in_sizes, int n_in,
                              void* d_out, int out_size, void* d_ws, size_t ws_size,
                              hipStream_t stream) {
    const float* img   = (const float*)d_in[0];   // (1, 2048, 2048) f32
    const float* noise = (const float*)d_in[1];   // (1, 4096, 4096) f32
    float* out = (float*)d_out;                   // (1, 4096, 4096) f32

    dim3 grid(N / TILE, N / TILE);  // 128 x 128 blocks
    TensorAugment_79216376807666_kernel<<<grid, 256, 0, stream>>>(img, noise, out);
}

// Round 2
// 148.855 us; speedup vs baseline: 1.8400x; 1.8400x over previous
//
#include <hip/hip_runtime.h>
#include <math.h>

#define N     4096
#define NIMG  2048
#define TX    56          // output tile width
#define TY    32          // output tile height
#define DW    64          // D-region width  = TX + 8  (1 lane per column)
#define DH    40          // D-region height = TY + 8
#define IPR   36          // img patch rows allocated (max needed ~34)
#define IPP   25          // img patch pitch (odd -> conflict-free)
#define STP   41          // ST pitch over rows (odd -> conflict-free)
#define VP    65          // V pitch (65 = 1 mod 32 -> spread banks in stage 3)
#define S2P   57          // transpose-out pitch (odd)

// Gaussian kernel sigma=1, r=4 (double-precision eval of reference formula)
#define KW0 0.00013383063f
#define KW1 0.00443186160f
#define KW2 0.05399112800f
#define KW3 0.24197144000f
#define KW4 0.39894346870f

__device__ __forceinline__ int symi(int g) {
    // np.pad mode='symmetric': -1 -> 0, -2 -> 1; N -> N-1
    g = (g < 0) ? (-1 - g) : g;
    g = (g >= N) ? (2 * N - 1 - g) : g;
    return g;
}

__global__ __launch_bounds__(256, 7)
void TensorAugment_79216376807666_kernel(const float* __restrict__ img,
                                         const float* __restrict__ noise,
                                         float* __restrict__ out) {
    __shared__ float IP[IPR * IPP];   // img patch (clamp-guarded)       3.6 KB
    __shared__ float ST[DW * STP];    // D tile, column-major [c][row]  10.5 KB
    __shared__ float V[TY * VP];      // vertically blurred, row-major   8.3 KB

    const int tid  = threadIdx.x;
    const int lane = tid & 63;
    const int wave = tid >> 6;
    const int x0 = blockIdx.x * TX;
    const int y0 = blockIdx.y * TY;

    const float kk[9] = {KW0, KW1, KW2, KW3, KW4, KW3, KW2, KW1, KW0};

    // ---- block-uniform index ranges (sym-mapped) ----
    int gxa = x0 - 4, gxb = x0 + DW - 5;                 // D-region gx span
    int mxa = symi(gxa), mxb = symi(gxb);
    int gxmin = min(mxa, mxb), gxmax = max(mxa, mxb);
    if (gxa <= 0) gxmin = 0;
    if (gxb >= N - 1) gxmax = N - 1;
    int umin = (N - 1) - gxmax, umax = (N - 1) - gxmin;  // img-row coords (x2 space)
    int r0min = (umin - 1) >> 1;
    int r0max = (umax - 1) >> 1;
    int nrows = r0max - r0min + 2;                        // staged rows (<=34)

    int gya = y0 - 4, gyb = y0 + DH - 5;
    int mya = symi(gya), myb = symi(gyb);
    int gymin = min(mya, myb), gymax = max(mya, myb);
    if (gya <= 0) gymin = 0;
    if (gyb >= N - 1) gymax = N - 1;
    int c0min = (gymin - 1) >> 1;
    int c0max = (gymax - 1) >> 1;
    int ncols = c0max - c0min + 2;                        // staged cols (<=22)

    // ---- stage 0: coalesced img patch load (with clamp guards) ----
    {
        int j  = tid & 31;
        int rr = tid >> 5;
        for (int r = rr; r < nrows; r += 8) {
            if (j < ncols) {
                int ir = min(max(r0min + r, 0), NIMG - 1);
                int ic = min(max(c0min + j, 0), NIMG - 1);
                IP[r * IPP + j] = img[ir * NIMG + ic];
            }
        }
    }
    __syncthreads();

    // ---- stage 1: D = bilinear(rot) + noise, column-major into ST ----
    {
        int c   = lane;                       // D column 0..63
        int gxm = symi(x0 - 4 + c);
        int u   = (N - 1) - gxm;
        int r0  = (u - 1) >> 1;
        float wr1 = (u & 1) ? 0.25f : 0.75f;
        float wr0 = 1.0f - wr1;
        int a0 = (r0 - r0min) * IPP;          // staged row offset (guarded, >=0)

#pragma unroll
        for (int k = 0; k < 10; ++k) {
            int row = wave + 4 * k;           // 0..39
            int gym = symi(y0 - 4 + row);
            int c0  = (gym - 1) >> 1;
            float wc1 = (gym & 1) ? 0.25f : 0.75f;
            float wc0 = 1.0f - wc1;
            int jc = c0 - c0min;              // guarded, >=0

            float nv = noise[gym * N + gxm];  // coalesced
            float f0 = IP[a0 + jc],       f1 = IP[a0 + jc + 1];        // ds_read2
            float f2 = IP[a0 + IPP + jc], f3 = IP[a0 + IPP + jc + 1];  // ds_read2
            float top = fmaf(wc0, f0, wc1 * f1);
            float bot = fmaf(wc0, f2, wc1 * f3);
            float d = fmaf(wr0, top, wr1 * bot) + 0.01f * nv;
            ST[c * STP + row] = d;
        }
    }
    __syncthreads();

    // ---- stage 2: vertical blur, sliding window (8 outputs/thread) ----
    {
        int c = lane;
        int rbase = wave * 8;
        float win[16];
        int ab = c * STP + rbase;
#pragma unroll
        for (int k = 0; k < 16; ++k) win[k] = ST[ab + k];  // contiguous -> ds_read2
#pragma unroll
        for (int j = 0; j < 8; ++j) {
            float acc = 0.0f;
#pragma unroll
            for (int i = 0; i < 9; ++i) acc = fmaf(kk[i], win[j + i], acc);
            V[(rbase + j) * VP + c] = acc;
        }
    }
    __syncthreads();

    // ---- stage 3: horizontal blur + relu + log1p, 7 outputs/thread ----
    {
        int r = tid >> 3;                     // 0..31
        int s = tid & 7;                      // 0..7
        float w2[15];
        int vb = r * VP + s * 7;
#pragma unroll
        for (int k = 0; k < 15; ++k) w2[k] = V[vb + k];    // contiguous -> ds_read2
#pragma unroll
        for (int j = 0; j < 7; ++j) {
            float acc = 0.0f;
#pragma unroll
            for (int i = 0; i < 9; ++i) acc = fmaf(kk[i], w2[j + i], acc);
            acc = fmaxf(acc, 0.0f);
            ST[r * S2P + s * 7 + j] = __logf(1.0f + acc);  // reuse ST as transpose buf
        }
    }
    __syncthreads();

    // ---- stage 4: coalesced store ----
    for (int r = wave; r < TY; r += 4) {
        int gx = x0 + lane;
        if (lane < TX && gx < N)
            out[(y0 + r) * N + gx] = ST[r * S2P + lane];
    }
}

extern "C" void kernel_launch(void* const* d_in, const int* in_sizes, int n_in,
                              void* d_out, int out_size, void* d_ws, size_t ws_size,
                              hipStream_t stream) {
    const float* img   = (const float*)d_in[0];   // (1, 2048, 2048) f32
    const float* noise = (const float*)d_in[1];   // (1, 4096, 4096) f32
    float* out = (float*)d_out;                   // (1, 4096, 4096) f32

    dim3 grid((N + TX - 1) / TX, N / TY);         // 74 x 128 blocks
    TensorAugment_79216376807666_kernel<<<grid, 256, 0, stream>>>(img, noise, out);
}